// Round 5
// baseline (57.266 us; speedup 1.0000x reference)
//
#include <hip/hip_runtime.h>

typedef float f4 __attribute__((ext_vector_type(4)));

constexpr int D  = 128;
constexpr int B  = 1024;
constexpr int S1 = 25;    // inner fanout (hop2 -> hop1)
constexpr int S2 = 10;    // outer fanout (hop1 -> hop0)

// ---------------------------------------------------------------------------
// Layer-0 via global_load_lds staging (R3 structure, proven 55.2 us), with
// NON-TEMPORAL cache policy (aux=2 -> CPol NT) on the neighbor-row staging:
// the 131 MB random-row gather has zero reuse, so skip L2/L3 allocation.
// This is the final falsification test of "cap is cache-side MSHR/alloc churn"
// vs "cap is DRAM row-activate service rate". Null result => roofline.
// ---------------------------------------------------------------------------
constexpr int RPB   = 8;
constexpr int NROWS = 108;   // 100 neighbor rows (per round) + 8 self rows

#define GLD16NT(src, dst) __builtin_amdgcn_global_load_lds(                    \
    (const __attribute__((address_space(1))) void*)(src),                      \
    (__attribute__((address_space(3))) void*)(dst), 16, 0, 2 /* NT */)

__device__ __forceinline__ void load_pair(const float* feat, int gi, int lane,
                                          float* nbuf, int dst_pair)
{
    // per-lane global source (row gi, 16B chunk lane&31); wave-uniform LDS base
    const float* src = feat + (size_t)gi * D + (lane & 31) * 4;
    GLD16NT(src, nbuf + dst_pair * (2 * D));
}

__device__ __forceinline__ void reduce25(int t, const float* nbuf,
                                         float (*lds_m)[D], int r2)
{
    // wave r owns output r of this round; lane-halves split s = [0,13)/[13,25)
    const int c = t & 31;
    const int g = t >> 5;
    const int r = g >> 1;        // == wave id
    const int h = g & 1;
    f4 acc = {0.f, 0.f, 0.f, 0.f};
    #pragma unroll
    for (int k = 0; k < 13; ++k) {
        const int s = h * 13 + k;
        if (s < 25)
            acc += *(const f4*)(nbuf + (r * 25 + s) * D + c * 4);
    }
    acc.x += __shfl_xor(acc.x, 32);
    acc.y += __shfl_xor(acc.y, 32);
    acc.z += __shfl_xor(acc.z, 32);
    acc.w += __shfl_xor(acc.w, 32);
    if (h == 0)
        *(f4*)(&lds_m[r2 * 4 + r][c * 4]) = acc * (1.f / 25.f);
}

__device__ __forceinline__ void matmul_store(
    int t, const float* nbuf, const float (*lds_m)[D],
    const float* __restrict__ Ws, const float* __restrict__ Wn,
    float* __restrict__ outrows)
{
    const int d  = t & 127;
    const int rh = t >> 7;                     // 4-row half
    const float* hbase = nbuf + (100 + rh * 4) * D;
    float acc[4] = {0.f, 0.f, 0.f, 0.f};

    #pragma unroll 4
    for (int k4 = 0; k4 < D / 4; ++k4) {
        const int k = k4 * 4;
        const float ws0 = Ws[(k + 0) * D + d], ws1 = Ws[(k + 1) * D + d],
                    ws2 = Ws[(k + 2) * D + d], ws3 = Ws[(k + 3) * D + d];
        const float wn0 = Wn[(k + 0) * D + d], wn1 = Wn[(k + 1) * D + d],
                    wn2 = Wn[(k + 2) * D + d], wn3 = Wn[(k + 3) * D + d];
        #pragma unroll
        for (int r = 0; r < 4; ++r) {
            const f4 hv = *(const f4*)(hbase + r * D + k);
            const f4 mv = *(const f4*)(&lds_m[rh * 4 + r][k]);
            acc[r] += hv.x * ws0 + hv.y * ws1 + hv.z * ws2 + hv.w * ws3
                    + mv.x * wn0 + mv.y * wn1 + mv.z * wn2 + mv.w * wn3;
        }
    }
    #pragma unroll
    for (int r = 0; r < 4; ++r)
        outrows[(size_t)(rh * 4 + r) * D + d] = fmaxf(acc[r], 0.f);
}

__global__ __launch_bounds__(256, 2) void layer0_kernel(
    const float* __restrict__ feat,
    const int* __restrict__ s0, const int* __restrict__ s1,
    const int* __restrict__ s2,
    const float* __restrict__ Ws0, const float* __restrict__ Wn0,
    float* __restrict__ nh1, float* __restrict__ nh0)
{
    __shared__ float nbuf[NROWS * D];      // 54 KB
    __shared__ float lds_m[RPB][D];        // 4 KB

    const int NB1  = (B * S2) / RPB;       // 1280
    const int b    = blockIdx.x;
    const int t    = threadIdx.x;
    const int w    = t >> 6;
    const int lane = t & 63;
    const int half = lane >> 5;

    if (b < NB1) {
        const int base = b * RPB;
        const int* __restrict__ nidx = s2 + (size_t)base * S1;
        const int* __restrict__ sidx = s1 + base;

        // prefetch ALL pair indices for both rounds (no idx->load stalls later)
        int gi0[14], gi1[13];
        #pragma unroll
        for (int i = 0; i < 14; ++i) {
            const int p = w + i * 4;
            if (p < 54) {
                const int j = 2 * p + half;          // rows 0-99 neigh, 100-107 self
                gi0[i] = (j < 100) ? nidx[j] : sidx[j - 100];
            }
        }
        #pragma unroll
        for (int i = 0; i < 13; ++i) {
            const int p = w + i * 4;
            if (p < 50) gi1[i] = nidx[100 + 2 * p + half];
        }

        // round 0: outputs 0-3 neighbors (rows 0-99) + all 8 self (rows 100-107)
        #pragma unroll
        for (int i = 0; i < 14; ++i) {
            const int p = w + i * 4;
            if (p < 54) load_pair(feat, gi0[i], lane, nbuf, p);
        }
        __syncthreads();
        reduce25(t, nbuf, lds_m, 0);
        __syncthreads();

        // round 1: outputs 4-7 neighbors (rows 0-99 restaged)
        #pragma unroll
        for (int i = 0; i < 13; ++i) {
            const int p = w + i * 4;
            if (p < 50) load_pair(feat, gi1[i], lane, nbuf, p);
        }
        __syncthreads();
        reduce25(t, nbuf, lds_m, 1);
        __syncthreads();

        matmul_store(t, nbuf, lds_m, Ws0, Wn0, nh1 + (size_t)base * D);
    } else {
        const int base = (b - NB1) * RPB;
        const int* __restrict__ nidx = s1 + (size_t)base * S2;
        const int* __restrict__ sidx = s0 + base;

        // single round: 80 neighbor rows (0-79) + 8 self rows at 100-107
        int gi[11];
        #pragma unroll
        for (int i = 0; i < 11; ++i) {
            const int p = w + i * 4;               // p in [0,44) always
            const int j = 2 * p + half;
            gi[i] = (j < 80) ? nidx[j] : sidx[j - 80];
        }
        #pragma unroll
        for (int i = 0; i < 11; ++i) {
            const int p    = w + i * 4;
            const int dstp = (p < 40) ? p : (50 + (p - 40));   // self -> rows 100+
            load_pair(feat, gi[i], lane, nbuf, dstp);
        }
        __syncthreads();
        {   // reduce: 32-lane group g owns output g (10 rows, no shfl needed)
            const int o = t >> 5, c = t & 31;
            f4 acc = {0.f, 0.f, 0.f, 0.f};
            #pragma unroll
            for (int s = 0; s < S2; ++s)
                acc += *(const f4*)(nbuf + (o * S2 + s) * D + c * 4);
            *(f4*)(&lds_m[o][c * 4]) = acc * (1.f / S2);
        }
        __syncthreads();
        matmul_store(t, nbuf, lds_m, Ws0, Wn0, nh0 + (size_t)base * D);
    }
}

// ---------------------------------------------------------------------------
// Layer 1: self = nh0 rows direct; mean over S2 contiguous nh1 rows; identity.
// ---------------------------------------------------------------------------
constexpr int RPB_L = 4;
__global__ __launch_bounds__(128) void layer1_kernel(
    const float* __restrict__ nh0, const float* __restrict__ nh1,
    const float* __restrict__ Ws1, const float* __restrict__ Wn1,
    float* __restrict__ out)
{
    __shared__ float lds_h[RPB_L][D];
    __shared__ float lds_m[RPB_L][D];
    const int tid  = threadIdx.x;
    const int base = blockIdx.x * RPB_L;

    #pragma unroll
    for (int r = 0; r < RPB_L; ++r) {
        const int row = base + r;
        lds_h[r][tid] = nh0[(long)row * D + tid];
        float s = 0.f;
        #pragma unroll
        for (int n = 0; n < S2; ++n)
            s += nh1[((long)row * S2 + n) * D + tid];
        lds_m[r][tid] = s * (1.f / S2);
    }
    __syncthreads();

    const int d = tid;
    float acc[RPB_L];
    #pragma unroll
    for (int r = 0; r < RPB_L; ++r) acc[r] = 0.f;

    #pragma unroll 4
    for (int k4 = 0; k4 < D / 4; ++k4) {
        const int k = k4 * 4;
        const float ws0 = Ws1[(k + 0) * D + d];
        const float ws1 = Ws1[(k + 1) * D + d];
        const float ws2 = Ws1[(k + 2) * D + d];
        const float ws3 = Ws1[(k + 3) * D + d];
        const float wn0 = Wn1[(k + 0) * D + d];
        const float wn1 = Wn1[(k + 1) * D + d];
        const float wn2 = Wn1[(k + 2) * D + d];
        const float wn3 = Wn1[(k + 3) * D + d];
        #pragma unroll
        for (int r = 0; r < RPB_L; ++r) {
            const f4 hv = *(const f4*)(&lds_h[r][k]);
            const f4 mv = *(const f4*)(&lds_m[r][k]);
            acc[r] += hv.x * ws0 + hv.y * ws1 + hv.z * ws2 + hv.w * ws3
                    + mv.x * wn0 + mv.y * wn1 + mv.z * wn2 + mv.w * wn3;
        }
    }

    #pragma unroll
    for (int r = 0; r < RPB_L; ++r)
        out[(long)(base + r) * D + d] = acc[r];
}

extern "C" void kernel_launch(void* const* d_in, const int* in_sizes, int n_in,
                              void* d_out, int out_size, void* d_ws, size_t ws_size,
                              hipStream_t stream)
{
    const float* feat = (const float*)d_in[0];
    const float* Ws0  = (const float*)d_in[1];
    const float* Wn0  = (const float*)d_in[2];
    const float* Ws1  = (const float*)d_in[3];
    const float* Wn1  = (const float*)d_in[4];
    const int*   s0   = (const int*)d_in[5];
    const int*   s1   = (const int*)d_in[6];
    const int*   s2   = (const int*)d_in[7];
    float* out = (float*)d_out;

    float* nh1 = (float*)d_ws;                   // [B*S2, D]
    float* nh0 = nh1 + (size_t)(B * S2) * D;     // [B, D]

    const int grid0 = (B * S2) / RPB + B / RPB;  // 1280 + 128 = 1408
    layer0_kernel<<<grid0, 256, 0, stream>>>(feat, s0, s1, s2, Ws0, Wn0, nh1, nh0);
    layer1_kernel<<<B / RPB_L, 128, 0, stream>>>(nh0, nh1, Ws1, Wn1, out);
}

// Round 6
// 54.689 us; speedup vs baseline: 1.0471x; 1.0471x over previous
//
#include <hip/hip_runtime.h>

typedef float f4 __attribute__((ext_vector_type(4)));

constexpr int D  = 128;
constexpr int B  = 1024;
constexpr int S1 = 25;    // inner fanout (hop2 -> hop1)
constexpr int S2 = 10;    // outer fanout (hop1 -> hop0)

// ---------------------------------------------------------------------------
// FINAL (session-best, 55.21 us): layer-0 via global_load_lds staging.
//   RPB=8 output rows per block; 1280 nh1 blocks + 128 nh0 blocks = 1408.
//   Roofline evidence: R0 (reg-accum) 55.211, R3 (this) 55.210, R4 (fused)
//   57.0, R5 (NT) 57.3 -> random-512B-row gather service rate (~2.9 TB/s,
//   ~45% of streaming ceiling, DRAM row-activate bound) is the wall.
//   Default cache policy (aux=0): L2 catches the ~12% duplicate indices.
// ---------------------------------------------------------------------------
constexpr int RPB   = 8;
constexpr int NROWS = 108;   // 100 neighbor rows (per round) + 8 self rows

#define GLD16(src, dst) __builtin_amdgcn_global_load_lds(                      \
    (const __attribute__((address_space(1))) void*)(src),                      \
    (__attribute__((address_space(3))) void*)(dst), 16, 0, 0)

__device__ __forceinline__ void load_pair(const float* feat, int gi, int lane,
                                          float* nbuf, int dst_pair)
{
    // per-lane global source (row gi, 16B chunk lane&31); wave-uniform LDS base
    const float* src = feat + (size_t)gi * D + (lane & 31) * 4;
    GLD16(src, nbuf + dst_pair * (2 * D));
}

__device__ __forceinline__ void reduce25(int t, const float* nbuf,
                                         float (*lds_m)[D], int r2)
{
    // wave r owns output r of this round; lane-halves split s = [0,13)/[13,25)
    const int c = t & 31;
    const int g = t >> 5;
    const int r = g >> 1;        // == wave id
    const int h = g & 1;
    f4 acc = {0.f, 0.f, 0.f, 0.f};
    #pragma unroll
    for (int k = 0; k < 13; ++k) {
        const int s = h * 13 + k;
        if (s < 25)
            acc += *(const f4*)(nbuf + (r * 25 + s) * D + c * 4);
    }
    acc.x += __shfl_xor(acc.x, 32);
    acc.y += __shfl_xor(acc.y, 32);
    acc.z += __shfl_xor(acc.z, 32);
    acc.w += __shfl_xor(acc.w, 32);
    if (h == 0)
        *(f4*)(&lds_m[r2 * 4 + r][c * 4]) = acc * (1.f / 25.f);
}

__device__ __forceinline__ void matmul_store(
    int t, const float* nbuf, const float (*lds_m)[D],
    const float* __restrict__ Ws, const float* __restrict__ Wn,
    float* __restrict__ outrows)
{
    const int d  = t & 127;
    const int rh = t >> 7;                     // 4-row half
    const float* hbase = nbuf + (100 + rh * 4) * D;
    float acc[4] = {0.f, 0.f, 0.f, 0.f};

    #pragma unroll 4
    for (int k4 = 0; k4 < D / 4; ++k4) {
        const int k = k4 * 4;
        const float ws0 = Ws[(k + 0) * D + d], ws1 = Ws[(k + 1) * D + d],
                    ws2 = Ws[(k + 2) * D + d], ws3 = Ws[(k + 3) * D + d];
        const float wn0 = Wn[(k + 0) * D + d], wn1 = Wn[(k + 1) * D + d],
                    wn2 = Wn[(k + 2) * D + d], wn3 = Wn[(k + 3) * D + d];
        #pragma unroll
        for (int r = 0; r < 4; ++r) {
            const f4 hv = *(const f4*)(hbase + r * D + k);
            const f4 mv = *(const f4*)(&lds_m[rh * 4 + r][k]);
            acc[r] += hv.x * ws0 + hv.y * ws1 + hv.z * ws2 + hv.w * ws3
                    + mv.x * wn0 + mv.y * wn1 + mv.z * wn2 + mv.w * wn3;
        }
    }
    #pragma unroll
    for (int r = 0; r < 4; ++r)
        outrows[(size_t)(rh * 4 + r) * D + d] = fmaxf(acc[r], 0.f);
}

__global__ __launch_bounds__(256, 2) void layer0_kernel(
    const float* __restrict__ feat,
    const int* __restrict__ s0, const int* __restrict__ s1,
    const int* __restrict__ s2,
    const float* __restrict__ Ws0, const float* __restrict__ Wn0,
    float* __restrict__ nh1, float* __restrict__ nh0)
{
    __shared__ float nbuf[NROWS * D];      // 54 KB
    __shared__ float lds_m[RPB][D];        // 4 KB

    const int NB1  = (B * S2) / RPB;       // 1280
    const int b    = blockIdx.x;
    const int t    = threadIdx.x;
    const int w    = t >> 6;
    const int lane = t & 63;
    const int half = lane >> 5;

    if (b < NB1) {
        const int base = b * RPB;
        const int* __restrict__ nidx = s2 + (size_t)base * S1;
        const int* __restrict__ sidx = s1 + base;

        // prefetch ALL pair indices for both rounds (no idx->load stalls later)
        int gi0[14], gi1[13];
        #pragma unroll
        for (int i = 0; i < 14; ++i) {
            const int p = w + i * 4;
            if (p < 54) {
                const int j = 2 * p + half;          // rows 0-99 neigh, 100-107 self
                gi0[i] = (j < 100) ? nidx[j] : sidx[j - 100];
            }
        }
        #pragma unroll
        for (int i = 0; i < 13; ++i) {
            const int p = w + i * 4;
            if (p < 50) gi1[i] = nidx[100 + 2 * p + half];
        }

        // round 0: outputs 0-3 neighbors (rows 0-99) + all 8 self (rows 100-107)
        #pragma unroll
        for (int i = 0; i < 14; ++i) {
            const int p = w + i * 4;
            if (p < 54) load_pair(feat, gi0[i], lane, nbuf, p);
        }
        __syncthreads();
        reduce25(t, nbuf, lds_m, 0);
        __syncthreads();

        // round 1: outputs 4-7 neighbors (rows 0-99 restaged)
        #pragma unroll
        for (int i = 0; i < 13; ++i) {
            const int p = w + i * 4;
            if (p < 50) load_pair(feat, gi1[i], lane, nbuf, p);
        }
        __syncthreads();
        reduce25(t, nbuf, lds_m, 1);
        __syncthreads();

        matmul_store(t, nbuf, lds_m, Ws0, Wn0, nh1 + (size_t)base * D);
    } else {
        const int base = (b - NB1) * RPB;
        const int* __restrict__ nidx = s1 + (size_t)base * S2;
        const int* __restrict__ sidx = s0 + base;

        // single round: 80 neighbor rows (0-79) + 8 self rows at 100-107
        int gi[11];
        #pragma unroll
        for (int i = 0; i < 11; ++i) {
            const int p = w + i * 4;               // p in [0,44) always
            const int j = 2 * p + half;
            gi[i] = (j < 80) ? nidx[j] : sidx[j - 80];
        }
        #pragma unroll
        for (int i = 0; i < 11; ++i) {
            const int p    = w + i * 4;
            const int dstp = (p < 40) ? p : (50 + (p - 40));   // self -> rows 100+
            load_pair(feat, gi[i], lane, nbuf, dstp);
        }
        __syncthreads();
        {   // reduce: 32-lane group g owns output g (10 rows, no shfl needed)
            const int o = t >> 5, c = t & 31;
            f4 acc = {0.f, 0.f, 0.f, 0.f};
            #pragma unroll
            for (int s = 0; s < S2; ++s)
                acc += *(const f4*)(nbuf + (o * S2 + s) * D + c * 4);
            *(f4*)(&lds_m[o][c * 4]) = acc * (1.f / S2);
        }
        __syncthreads();
        matmul_store(t, nbuf, lds_m, Ws0, Wn0, nh0 + (size_t)base * D);
    }
}

// ---------------------------------------------------------------------------
// Layer 1: self = nh0 rows direct; mean over S2 contiguous nh1 rows; identity.
// ---------------------------------------------------------------------------
constexpr int RPB_L = 4;
__global__ __launch_bounds__(128) void layer1_kernel(
    const float* __restrict__ nh0, const float* __restrict__ nh1,
    const float* __restrict__ Ws1, const float* __restrict__ Wn1,
    float* __restrict__ out)
{
    __shared__ float lds_h[RPB_L][D];
    __shared__ float lds_m[RPB_L][D];
    const int tid  = threadIdx.x;
    const int base = blockIdx.x * RPB_L;

    #pragma unroll
    for (int r = 0; r < RPB_L; ++r) {
        const int row = base + r;
        lds_h[r][tid] = nh0[(long)row * D + tid];
        float s = 0.f;
        #pragma unroll
        for (int n = 0; n < S2; ++n)
            s += nh1[((long)row * S2 + n) * D + tid];
        lds_m[r][tid] = s * (1.f / S2);
    }
    __syncthreads();

    const int d = tid;
    float acc[RPB_L];
    #pragma unroll
    for (int r = 0; r < RPB_L; ++r) acc[r] = 0.f;

    #pragma unroll 4
    for (int k4 = 0; k4 < D / 4; ++k4) {
        const int k = k4 * 4;
        const float ws0 = Ws1[(k + 0) * D + d];
        const float ws1 = Ws1[(k + 1) * D + d];
        const float ws2 = Ws1[(k + 2) * D + d];
        const float ws3 = Ws1[(k + 3) * D + d];
        const float wn0 = Wn1[(k + 0) * D + d];
        const float wn1 = Wn1[(k + 1) * D + d];
        const float wn2 = Wn1[(k + 2) * D + d];
        const float wn3 = Wn1[(k + 3) * D + d];
        #pragma unroll
        for (int r = 0; r < RPB_L; ++r) {
            const f4 hv = *(const f4*)(&lds_h[r][k]);
            const f4 mv = *(const f4*)(&lds_m[r][k]);
            acc[r] += hv.x * ws0 + hv.y * ws1 + hv.z * ws2 + hv.w * ws3
                    + mv.x * wn0 + mv.y * wn1 + mv.z * wn2 + mv.w * wn3;
        }
    }

    #pragma unroll
    for (int r = 0; r < RPB_L; ++r)
        out[(long)(base + r) * D + d] = acc[r];
}

extern "C" void kernel_launch(void* const* d_in, const int* in_sizes, int n_in,
                              void* d_out, int out_size, void* d_ws, size_t ws_size,
                              hipStream_t stream)
{
    const float* feat = (const float*)d_in[0];
    const float* Ws0  = (const float*)d_in[1];
    const float* Wn0  = (const float*)d_in[2];
    const float* Ws1  = (const float*)d_in[3];
    const float* Wn1  = (const float*)d_in[4];
    const int*   s0   = (const int*)d_in[5];
    const int*   s1   = (const int*)d_in[6];
    const int*   s2   = (const int*)d_in[7];
    float* out = (float*)d_out;

    float* nh1 = (float*)d_ws;                   // [B*S2, D]
    float* nh0 = nh1 + (size_t)(B * S2) * D;     // [B, D]

    const int grid0 = (B * S2) / RPB + B / RPB;  // 1280 + 128 = 1408
    layer0_kernel<<<grid0, 256, 0, stream>>>(feat, s0, s1, s2, Ws0, Wn0, nh1, nh0);
    layer1_kernel<<<B / RPB_L, 128, 0, stream>>>(nh0, nh1, Ws1, Wn1, out);
}